// Round 4
// baseline (198.714 us; speedup 1.0000x reference)
//
#include <hip/hip_runtime.h>
#include <math.h>

#define B 32
#define Q 10000
#define C 80
#define TOPK 200

// ---------------------------------------------------------------------------
// Fast double-precision exp for x in [-40, 0]  (bit-identical to R2/R3 version;
// used ONLY for the exact rescore of ~hundreds of candidates per batch)
// ---------------------------------------------------------------------------
__device__ __forceinline__ double fexp(double x) {
    const double L2E   = 1.4426950408889634;      // log2(e)
    const double SHIFT = 6755399441055744.0;      // 1.5 * 2^52
    const double LN2   = 0.6931471805599453;

    double y = x * L2E;
    double t = y + SHIFT;
    union { double d; unsigned long long u; } cv;
    cv.d = t;
    int n = (int)(unsigned int)cv.u;
    double f = y - (t - SHIFT);
    double r = f * LN2;

    double p = 2.755731922398589e-06;
    p = fma(p, r, 2.4801587301587302e-05);
    p = fma(p, r, 1.984126984126984e-04);
    p = fma(p, r, 1.3888888888888889e-03);
    p = fma(p, r, 8.333333333333333e-03);
    p = fma(p, r, 4.1666666666666664e-02);
    p = fma(p, r, 1.6666666666666666e-01);
    p = fma(p, r, 0.5);
    p = fma(p, r, 1.0);
    p = fma(p, r, 1.0);

    cv.d = p;
    cv.u += ((unsigned long long)(long long)n) << 52;
    return cv.d;
}

// ---------------------------------------------------------------------------
// Kernel 1 v4: APPROXIMATE f32 score pass. 64-thread block stages 64 rows in
// LDS (stride 81: conflict-free) via coalesced dwordx4, then thread t computes
// row t's f32 score bits with hardware v_exp_f32. rel error <= ~1e-5, only
// used for 13-bit bucket selection (bucket width 4.4% >> 1e-5).
// ---------------------------------------------------------------------------
__global__ __launch_bounds__(64) void score_kernel(
    const float* __restrict__ logits,
    unsigned int* __restrict__ scoreBits)
{
    __shared__ float sb[64 * 81];
    const int t = threadIdx.x;
    const int rowBase = blockIdx.x * 64;
    const float4* src = (const float4*)(logits + (long long)rowBase * C);

#pragma unroll
    for (int i = 0; i < 20; ++i) {
        int g = i * 64 + t;
        float4 v = src[g];
        int r = g / 20;
        int c = (g % 20) * 4;
        float* d = &sb[r * 81 + c];
        d[0] = v.x; d[1] = v.y; d[2] = v.z; d[3] = v.w;
    }
    __syncthreads();

    const float* row = &sb[t * 81];

    float m = row[0];
#pragma unroll 8
    for (int j = 1; j < 80; ++j) m = fmaxf(m, row[j]);

    float s = 0.0f;
#pragma unroll 8
    for (int j = 0; j < 80; ++j) s += __expf(row[j] - m);

    scoreBits[rowBase + t] = __float_as_uint(1.0f / s);   // score>0: order-monotone
}

// ---------------------------------------------------------------------------
// Kernel 2 v4: one block (1024 threads) per batch.
//   1) 2048-bucket histogram of approx bits; wave-0 suffix-scan threshold t;
//      collect at t-1 (provably superset of exact top-200)
//   2) EXACT f64 rescore of candidates (bit-identical fexp sum -> same keys
//      as R3), bitonic sort desc
//   3) top-200: recompute class, build sup bitmatrix, wave-parallel greedy
// ---------------------------------------------------------------------------
__global__ __launch_bounds__(1024) void nms_kernel(
    const unsigned int* __restrict__ scoreBits,
    const float* __restrict__ logits,
    const float* __restrict__ seg,
    int*         __restrict__ out)
{
    __shared__ unsigned int        hist[2048];
    __shared__ unsigned long long  skey[4096];
    __shared__ int   s_count;
    __shared__ unsigned int s_thresh;
    __shared__ int   cidx[TOPK];
    __shared__ int   ccls[TOPK];
    __shared__ float cx1[TOPK], cx2[TOPK];
    __shared__ unsigned long long sup[TOPK][4];
    __shared__ int   keepArr[TOPK];
    __shared__ int   s_keepCount;

    const int b   = blockIdx.x;
    const int tid = threadIdx.x;
    const unsigned int* bs = scoreBits + (long long)b * Q;

    for (int i = tid; i < 2048; i += 1024) hist[i] = 0;
    if (tid == 0) s_count = 0;
    __syncthreads();

    // histogram of top 13 bits of approx score pattern
    for (int i = tid; i < Q; i += 1024)
        atomicAdd(&hist[bs[i] >> 19], 1u);
    __syncthreads();

    // wave-0 two-level suffix scan -> threshold bucket t; collect at t-1
    if (tid < 64) {
        int cs = 0;
#pragma unroll
        for (int k = 0; k < 32; ++k) cs += (int)hist[tid * 32 + k];
        int S = cs;
#pragma unroll
        for (int off = 1; off < 64; off <<= 1) {
            int o = __shfl_down(S, off, 64);
            if (tid + off < 64) S += o;
        }
        unsigned long long bal = __ballot(S >= TOPK);
        int L = 63 - __clzll(bal);
        int accBase = (L < 63) ? __shfl(S, L + 1, 64) : 0;

        int h = (tid < 32) ? (int)hist[L * 32 + tid] : 0;
        int T = h;
#pragma unroll
        for (int off = 1; off < 32; off <<= 1) {
            int o = __shfl_down(T, off, 64);
            if (tid + off < 32) T += o;
        }
        unsigned long long bal2 = __ballot((tid < 32) && (accBase + T >= TOPK));
        int k2 = 63 - __clzll(bal2);
        if (tid == 0) {
            int th = L * 32 + k2;
            s_thresh = (unsigned)(th > 0 ? th - 1 : 0);   // -1 bucket safety margin
        }
    }
    __syncthreads();
    const unsigned int tc = s_thresh;

    // collect candidate row indices (ballot-compacted) into skey as raw q
    for (int i = tid; i < 10240; i += 1024) {
        bool pred = (i < Q) && ((bs[i] >> 19) >= tc);
        unsigned long long mask = __ballot(pred);
        int lane = tid & 63;
        int base;
        if (lane == 0) base = atomicAdd(&s_count, __popcll(mask));
        base = __shfl(base, 0, 64);
        if (pred) {
            int pos = base + __popcll(mask & ((1ull << lane) - 1ull));
            if (pos < 4096) skey[pos] = (unsigned long long)(unsigned)i;
        }
    }
    __syncthreads();

    const int count = min(s_count, 4096);

    // EXACT rescore of candidates: f64 fexp sum, bit-identical to R3 keys
    for (int c = tid; c < count; c += 1024) {
        int q = (int)(unsigned int)skey[c];
        const float4* rp = (const float4*)(logits + ((long long)b * Q + q) * C);
        float4 v[20];
#pragma unroll
        for (int i = 0; i < 20; ++i) v[i] = rp[i];

        float m = -INFINITY;
#pragma unroll
        for (int i = 0; i < 20; ++i) {
            m = fmaxf(m, v[i].x); m = fmaxf(m, v[i].y);
            m = fmaxf(m, v[i].z); m = fmaxf(m, v[i].w);
        }

        const double md = (double)m;
        double s = 0.0;
#pragma unroll
        for (int i = 0; i < 20; ++i) {             // sequential j=0..79 order == R3
            s += fexp((double)v[i].x - md);
            s += fexp((double)v[i].y - md);
            s += fexp((double)v[i].z - md);
            s += fexp((double)v[i].w - md);
        }

        float score = 1.0f / (float)s;
        skey[c] = ((unsigned long long)__float_as_uint(score) << 32) |
                  (unsigned long long)(0xFFFFFFFFu - (unsigned)q);
    }
    __syncthreads();

    int M = 256;
    while (M < count) M <<= 1;
    for (int i = tid; i < M; i += 1024)
        if (i >= count) skey[i] = 0;
    __syncthreads();

    // bitonic sort, descending
    for (int k = 2; k <= M; k <<= 1) {
        for (int j = k >> 1; j > 0; j >>= 1) {
            for (int t2 = tid; t2 < M; t2 += 1024) {
                int ixj = t2 ^ j;
                if (ixj > t2) {
                    unsigned long long a = skey[t2], c2 = skey[ixj];
                    bool desc = ((t2 & k) == 0);
                    bool sw   = desc ? (a < c2) : (a > c2);
                    if (sw) { skey[t2] = c2; skey[ixj] = a; }
                }
            }
            __syncthreads();
        }
    }

    // gather top-200 metadata; recompute class (strict > first-occurrence)
    if (tid < TOPK) {
        unsigned long long k = skey[tid];
        int q = (int)(0xFFFFFFFFu - (unsigned int)k);
        cidx[tid] = q;
        cx1[tid]  = seg[((long long)b * Q + q) * 2 + 0];
        cx2[tid]  = seg[((long long)b * Q + q) * 2 + 1];
        const float* row = logits + ((long long)b * Q + q) * C;
        float m = -INFINITY; int idx = 0;
#pragma unroll 8
        for (int j = 0; j < 80; ++j) {
            float v = row[j];
            if (v > m) { m = v; idx = j; }
        }
        ccls[tid] = idx;
    }
    __syncthreads();

    // suppression bitmatrix: sup[i][w] bit bb -> j = w*64+bb suppressed by i
    for (int w2 = tid; w2 < TOPK * 4; w2 += 1024) {
        int i  = w2 >> 2, ww = w2 & 3;
        int jb = ww * 64;
        float x1 = cx1[i], x2 = cx2[i];
        int   ci = ccls[i];
        unsigned long long bits = 0ull;
        for (int bb = 0; bb < 64; ++bb) {
            int j = jb + bb;
            if (j < TOPK && j > i) {
                float inter = fminf(x2, cx2[j]) - fmaxf(x1, cx1[j]);
                if (inter > 0.0f && ccls[j] == ci)
                    bits |= (1ull << bb);
            }
        }
        sup[i][ww] = bits;
    }
    __syncthreads();

    // greedy scan, wave-parallel: sup matrix register-resident in wave 0
    if (tid < 64) {
        unsigned long long w[13];
#pragma unroll
        for (int r = 0; r < 13; ++r) {
            int wg = r * 64 + tid;
            w[r] = (wg < TOPK * 4) ? sup[wg >> 2][wg & 3] : 0ull;
        }
        unsigned long long act[4]  = { ~0ull, ~0ull, ~0ull, ~0ull };
        unsigned long long kept[4] = { 0ull, 0ull, 0ull, 0ull };
#pragma unroll
        for (int g = 0; g < 13; ++g) {
#pragma unroll
            for (int s2 = 0; s2 < 16; ++s2) {
                const int p = g * 16 + s2;
                if (p >= TOPK) break;
                if ((act[p >> 6] >> (p & 63)) & 1ull) {
                    kept[p >> 6] |= 1ull << (p & 63);
                    unsigned long long s0 = __shfl(w[g], 4 * s2 + 0, 64);
                    unsigned long long s1 = __shfl(w[g], 4 * s2 + 1, 64);
                    unsigned long long sv = __shfl(w[g], 4 * s2 + 2, 64);
                    unsigned long long s3 = __shfl(w[g], 4 * s2 + 3, 64);
                    act[0] &= ~s0; act[1] &= ~s1; act[2] &= ~sv; act[3] &= ~s3;
                }
            }
        }
        int base0 = 0;
#pragma unroll
        for (int r = 0; r < 4; ++r) {
            int p = r * 64 + tid;
            if (p < TOPK && ((kept[r] >> tid) & 1ull)) {
                int slot = base0 + __popcll(kept[r] & ((1ull << tid) - 1ull));
                keepArr[slot] = cidx[p];
            }
            base0 += __popcll(kept[r]);
        }
        if (tid == 0) s_keepCount = base0;
    }
    __syncthreads();

    const int kc = s_keepCount;
    if (tid < TOPK) {
        out[b * TOPK + tid]       = (tid < kc) ? keepArr[tid] : -1;
        out[(B + b) * TOPK + tid] = 0;
    }
}

extern "C" void kernel_launch(void* const* d_in, const int* in_sizes, int n_in,
                              void* d_out, int out_size, void* d_ws, size_t ws_size,
                              hipStream_t stream)
{
    const float* logits = (const float*)d_in[0];   // [B,Q,C] fp32
    const float* seg    = (const float*)d_in[1];   // [B,Q,2] fp32
    int* out = (int*)d_out;                        // [2B, TOPK] int32

    unsigned int* scoreBits = (unsigned int*)d_ws;   // B*Q*4 bytes

    score_kernel<<<(B * Q) / 64, 64, 0, stream>>>(logits, scoreBits);
    nms_kernel<<<B, 1024, 0, stream>>>(scoreBits, logits, seg, out);
}

// Round 5
// 197.950 us; speedup vs baseline: 1.0039x; 1.0039x over previous
//
#include <hip/hip_runtime.h>
#include <math.h>

#define B 32
#define Q 10000
#define C 80
#define TOPK 200

// ---------------------------------------------------------------------------
// Fast double-precision exp for x in [-40, 0]  (bit-identical to R2/R3/R4;
// used ONLY for the exact rescore of ~hundreds of candidates per batch)
// ---------------------------------------------------------------------------
__device__ __forceinline__ double fexp(double x) {
    const double L2E   = 1.4426950408889634;      // log2(e)
    const double SHIFT = 6755399441055744.0;      // 1.5 * 2^52
    const double LN2   = 0.6931471805599453;

    double y = x * L2E;
    double t = y + SHIFT;
    union { double d; unsigned long long u; } cv;
    cv.d = t;
    int n = (int)(unsigned int)cv.u;
    double f = y - (t - SHIFT);
    double r = f * LN2;

    double p = 2.755731922398589e-06;
    p = fma(p, r, 2.4801587301587302e-05);
    p = fma(p, r, 1.984126984126984e-04);
    p = fma(p, r, 1.3888888888888889e-03);
    p = fma(p, r, 8.333333333333333e-03);
    p = fma(p, r, 4.1666666666666664e-02);
    p = fma(p, r, 1.6666666666666666e-01);
    p = fma(p, r, 0.5);
    p = fma(p, r, 1.0);
    p = fma(p, r, 1.0);

    cv.d = p;
    cv.u += ((unsigned long long)(long long)n) << 52;
    return cv.d;
}

// ---------------------------------------------------------------------------
// Kernel 1 v5: ONLINE approximate score pass, full occupancy.
// 128-thread block owns 128 rows; the 80 columns stream through LDS in five
// 16-column chunks (8.5 KB/block -> 16 blocks/CU -> 32 waves/CU). No max
// subtraction needed: logits are small, S=sum(exp(l)) and M=max(l) are
// accumulated online; score = exp(M)/S. Rel error ~1e-6, consumed only by
// 13-bit bucketing with a full-bucket (3.1%) safety margin.
// ---------------------------------------------------------------------------
__global__ __launch_bounds__(128) void score_kernel(
    const float* __restrict__ logits,
    unsigned int* __restrict__ scoreBits)
{
    __shared__ float sb[128 * 17];                 // stride 17: odd -> read-conflict-free
    const int t = threadIdx.x;
    const int rowBase = blockIdx.x * 128;
    const float* base = logits + (long long)rowBase * C;

    float M = -INFINITY, S = 0.0f;
#pragma unroll
    for (int c = 0; c < 5; ++c) {
        __syncthreads();                           // LDS reusable (no-op cost at c=0)
        // stage cols [16c,16c+16) of all 128 rows: 512 float4s, coalesced
#pragma unroll
        for (int k = 0; k < 4; ++k) {
            int e  = k * 128 + t;                  // 0..511
            int r  = e >> 2;                       // row within tile
            int jj = e & 3;                        // f4 within chunk
            float4 v = *(const float4*)(base + (long long)r * C + c * 16 + jj * 4);
            float* d = &sb[r * 17 + jj * 4];
            d[0] = v.x; d[1] = v.y; d[2] = v.z; d[3] = v.w;
        }
        __syncthreads();
        const float* row = &sb[t * 17];
#pragma unroll
        for (int j = 0; j < 16; ++j) {
            float v = row[j];
            M = fmaxf(M, v);
            S += __expf(v);
        }
    }
    scoreBits[rowBase + t] = __float_as_uint(__expf(M) / S);   // >0: order-monotone
}

// ---------------------------------------------------------------------------
// Kernel 2 v5 (same as verified R4): one block (1024 threads) per batch.
//   1) 2048-bucket histogram of approx bits; wave-0 suffix-scan threshold t;
//      collect at t-1 (provable superset of exact top-200)
//   2) EXACT f64 rescore of candidates (bit-identical fexp sum), bitonic sort
//   3) top-200: recompute class, sup bitmatrix, wave-parallel greedy scan
// ---------------------------------------------------------------------------
__global__ __launch_bounds__(1024) void nms_kernel(
    const unsigned int* __restrict__ scoreBits,
    const float* __restrict__ logits,
    const float* __restrict__ seg,
    int*         __restrict__ out)
{
    __shared__ unsigned int        hist[2048];
    __shared__ unsigned long long  skey[4096];
    __shared__ int   s_count;
    __shared__ unsigned int s_thresh;
    __shared__ int   cidx[TOPK];
    __shared__ int   ccls[TOPK];
    __shared__ float cx1[TOPK], cx2[TOPK];
    __shared__ unsigned long long sup[TOPK][4];
    __shared__ int   keepArr[TOPK];
    __shared__ int   s_keepCount;

    const int b   = blockIdx.x;
    const int tid = threadIdx.x;
    const unsigned int* bs = scoreBits + (long long)b * Q;

    for (int i = tid; i < 2048; i += 1024) hist[i] = 0;
    if (tid == 0) s_count = 0;
    __syncthreads();

    for (int i = tid; i < Q; i += 1024)
        atomicAdd(&hist[bs[i] >> 19], 1u);
    __syncthreads();

    // wave-0 two-level suffix scan -> threshold bucket; collect at bucket-1
    if (tid < 64) {
        int cs = 0;
#pragma unroll
        for (int k = 0; k < 32; ++k) cs += (int)hist[tid * 32 + k];
        int S = cs;
#pragma unroll
        for (int off = 1; off < 64; off <<= 1) {
            int o = __shfl_down(S, off, 64);
            if (tid + off < 64) S += o;
        }
        unsigned long long bal = __ballot(S >= TOPK);
        int L = 63 - __clzll(bal);
        int accBase = (L < 63) ? __shfl(S, L + 1, 64) : 0;

        int h = (tid < 32) ? (int)hist[L * 32 + tid] : 0;
        int T = h;
#pragma unroll
        for (int off = 1; off < 32; off <<= 1) {
            int o = __shfl_down(T, off, 64);
            if (tid + off < 32) T += o;
        }
        unsigned long long bal2 = __ballot((tid < 32) && (accBase + T >= TOPK));
        int k2 = 63 - __clzll(bal2);
        if (tid == 0) {
            int th = L * 32 + k2;
            s_thresh = (unsigned)(th > 0 ? th - 1 : 0);
        }
    }
    __syncthreads();
    const unsigned int tc = s_thresh;

    // collect candidate row indices (ballot-compacted)
    for (int i = tid; i < 10240; i += 1024) {
        bool pred = (i < Q) && ((bs[i] >> 19) >= tc);
        unsigned long long mask = __ballot(pred);
        int lane = tid & 63;
        int base;
        if (lane == 0) base = atomicAdd(&s_count, __popcll(mask));
        base = __shfl(base, 0, 64);
        if (pred) {
            int pos = base + __popcll(mask & ((1ull << lane) - 1ull));
            if (pos < 4096) skey[pos] = (unsigned long long)(unsigned)i;
        }
    }
    __syncthreads();

    const int count = min(s_count, 4096);

    // EXACT rescore: f64 fexp sum, bit-identical key bits to R2/R3/R4
    for (int c = tid; c < count; c += 1024) {
        int q = (int)(unsigned int)skey[c];
        const float4* rp = (const float4*)(logits + ((long long)b * Q + q) * C);
        float4 v[20];
#pragma unroll
        for (int i = 0; i < 20; ++i) v[i] = rp[i];

        float m = -INFINITY;
#pragma unroll
        for (int i = 0; i < 20; ++i) {
            m = fmaxf(m, v[i].x); m = fmaxf(m, v[i].y);
            m = fmaxf(m, v[i].z); m = fmaxf(m, v[i].w);
        }

        const double md = (double)m;
        double s = 0.0;
#pragma unroll
        for (int i = 0; i < 20; ++i) {
            s += fexp((double)v[i].x - md);
            s += fexp((double)v[i].y - md);
            s += fexp((double)v[i].z - md);
            s += fexp((double)v[i].w - md);
        }

        float score = 1.0f / (float)s;
        skey[c] = ((unsigned long long)__float_as_uint(score) << 32) |
                  (unsigned long long)(0xFFFFFFFFu - (unsigned)q);
    }
    __syncthreads();

    int M = 256;
    while (M < count) M <<= 1;
    for (int i = tid; i < M; i += 1024)
        if (i >= count) skey[i] = 0;
    __syncthreads();

    // bitonic sort, descending
    for (int k = 2; k <= M; k <<= 1) {
        for (int j = k >> 1; j > 0; j >>= 1) {
            for (int t2 = tid; t2 < M; t2 += 1024) {
                int ixj = t2 ^ j;
                if (ixj > t2) {
                    unsigned long long a = skey[t2], c2 = skey[ixj];
                    bool desc = ((t2 & k) == 0);
                    bool sw   = desc ? (a < c2) : (a > c2);
                    if (sw) { skey[t2] = c2; skey[ixj] = a; }
                }
            }
            __syncthreads();
        }
    }

    // top-200 metadata; class = strict-> first-occurrence argmax
    if (tid < TOPK) {
        unsigned long long k = skey[tid];
        int q = (int)(0xFFFFFFFFu - (unsigned int)k);
        cidx[tid] = q;
        cx1[tid]  = seg[((long long)b * Q + q) * 2 + 0];
        cx2[tid]  = seg[((long long)b * Q + q) * 2 + 1];
        const float* row = logits + ((long long)b * Q + q) * C;
        float m = -INFINITY; int idx = 0;
#pragma unroll 8
        for (int j = 0; j < 80; ++j) {
            float v = row[j];
            if (v > m) { m = v; idx = j; }
        }
        ccls[tid] = idx;
    }
    __syncthreads();

    // suppression bitmatrix
    for (int w2 = tid; w2 < TOPK * 4; w2 += 1024) {
        int i  = w2 >> 2, ww = w2 & 3;
        int jb = ww * 64;
        float x1 = cx1[i], x2 = cx2[i];
        int   ci = ccls[i];
        unsigned long long bits = 0ull;
        for (int bb = 0; bb < 64; ++bb) {
            int j = jb + bb;
            if (j < TOPK && j > i) {
                float inter = fminf(x2, cx2[j]) - fmaxf(x1, cx1[j]);
                if (inter > 0.0f && ccls[j] == ci)
                    bits |= (1ull << bb);
            }
        }
        sup[i][ww] = bits;
    }
    __syncthreads();

    // wave-parallel greedy scan, sup matrix register-resident in wave 0
    if (tid < 64) {
        unsigned long long w[13];
#pragma unroll
        for (int r = 0; r < 13; ++r) {
            int wg = r * 64 + tid;
            w[r] = (wg < TOPK * 4) ? sup[wg >> 2][wg & 3] : 0ull;
        }
        unsigned long long act[4]  = { ~0ull, ~0ull, ~0ull, ~0ull };
        unsigned long long kept[4] = { 0ull, 0ull, 0ull, 0ull };
#pragma unroll
        for (int g = 0; g < 13; ++g) {
#pragma unroll
            for (int s2 = 0; s2 < 16; ++s2) {
                const int p = g * 16 + s2;
                if (p >= TOPK) break;
                if ((act[p >> 6] >> (p & 63)) & 1ull) {
                    kept[p >> 6] |= 1ull << (p & 63);
                    unsigned long long s0 = __shfl(w[g], 4 * s2 + 0, 64);
                    unsigned long long s1 = __shfl(w[g], 4 * s2 + 1, 64);
                    unsigned long long sv = __shfl(w[g], 4 * s2 + 2, 64);
                    unsigned long long s3 = __shfl(w[g], 4 * s2 + 3, 64);
                    act[0] &= ~s0; act[1] &= ~s1; act[2] &= ~sv; act[3] &= ~s3;
                }
            }
        }
        int base0 = 0;
#pragma unroll
        for (int r = 0; r < 4; ++r) {
            int p = r * 64 + tid;
            if (p < TOPK && ((kept[r] >> tid) & 1ull)) {
                int slot = base0 + __popcll(kept[r] & ((1ull << tid) - 1ull));
                keepArr[slot] = cidx[p];
            }
            base0 += __popcll(kept[r]);
        }
        if (tid == 0) s_keepCount = base0;
    }
    __syncthreads();

    const int kc = s_keepCount;
    if (tid < TOPK) {
        out[b * TOPK + tid]       = (tid < kc) ? keepArr[tid] : -1;
        out[(B + b) * TOPK + tid] = 0;
    }
}

extern "C" void kernel_launch(void* const* d_in, const int* in_sizes, int n_in,
                              void* d_out, int out_size, void* d_ws, size_t ws_size,
                              hipStream_t stream)
{
    const float* logits = (const float*)d_in[0];   // [B,Q,C] fp32
    const float* seg    = (const float*)d_in[1];   // [B,Q,2] fp32
    int* out = (int*)d_out;                        // [2B, TOPK] int32

    unsigned int* scoreBits = (unsigned int*)d_ws; // B*Q*4 bytes

    score_kernel<<<(B * Q) / 128, 128, 0, stream>>>(logits, scoreBits);
    nms_kernel<<<B, 1024, 0, stream>>>(scoreBits, logits, seg, out);
}